// Round 5
// baseline (296.720 us; speedup 1.0000x reference)
//
#include <hip/hip_runtime.h>

#define C_IN  128
#define C_RES 64
#define D     512
#define DD    (D * D)          // 262144 floats per c-slice
#define NC4   (DD / 4)         // 65536 float4 chunks per (o,i) plane
#define TILE4 1024             // float4 per K1 tile (16 KB)

// ---------------------------------------------------------------------------
// K1: burst-experiment colsum. 1536 blocks x 256 (24 waves/CU, the measured
// occupancy sweet spot). W1 -> 16 partial planes (8 c each): blocks 0..1023,
// tile = b>>4 (slow), cgroup = b&15 (fast) so the ~512 resident blocks span
// ~32 consecutive tiles x all cgroups = a dense sliding ~512KB window in
// EVERY c-slice. W2 -> 8 partial planes: blocks 1024..1535.
// Per c-step each WAVE reads 4KB contiguous via 4 coalesced float4 loads
// (vs 1KB in all previous rounds) -- tests the DRAM row/activate hypothesis
// for the ~77us floor (occ 13%->95us, 59%->77us, VALU ~2%, no conflicts).
// Also: zero diff1, init out = relu(x) + bc2 (tail scatters into out).
// ---------------------------------------------------------------------------
__global__ __launch_bounds__(256)
void sum_init_kernel(const float* __restrict__ W1,
                     const float* __restrict__ W2,
                     const float* __restrict__ x,
                     const float* __restrict__ bc2,
                     float* __restrict__ Sp,        // 24 * DD floats
                     float* __restrict__ diff1,
                     float* __restrict__ out) {
    const int t = threadIdx.x;
    const int b = blockIdx.x;                      // 0..1535
    const float4* __restrict__ src;
    float4* __restrict__ dst;
    if (b < 1024) {                                // W1: 64 tiles x 16 cgroups
        const int tile = b >> 4, g = b & 15;
        src = (const float4*)W1 + (size_t)(g * 8) * NC4 + tile * TILE4;
        dst = (float4*)Sp + (size_t)g * NC4 + tile * TILE4;
    } else {                                       // W2: 64 tiles x 8 cgroups
        const int b2 = b - 1024;
        const int tile = b2 >> 3, g = b2 & 7;
        src = (const float4*)W2 + (size_t)(g * 8) * NC4 + tile * TILE4;
        dst = (float4*)Sp + (size_t)(16 + g) * NC4 + tile * TILE4;
    }
    // wave w owns contiguous float4 range [w*256, w*256+256) of the tile;
    // lane l loads o0, o0+64, o0+128, o0+192 -> 4 coalesced 1KB instrs = 4KB.
    const int o0 = ((t >> 6) << 8) + (t & 63);
    float4 a0 = make_float4(0.f, 0.f, 0.f, 0.f);
    float4 a1 = a0, a2 = a0, a3 = a0;
#pragma unroll
    for (int cc = 0; cc < 8; ++cc) {
        const float4* p = src + (size_t)cc * NC4;
        float4 w0 = p[o0];
        float4 w1 = p[o0 + 64];
        float4 w2 = p[o0 + 128];
        float4 w3 = p[o0 + 192];
        a0.x += w0.x; a0.y += w0.y; a0.z += w0.z; a0.w += w0.w;
        a1.x += w1.x; a1.y += w1.y; a1.z += w1.z; a1.w += w1.w;
        a2.x += w2.x; a2.y += w2.y; a2.z += w2.z; a2.w += w2.w;
        a3.x += w3.x; a3.y += w3.y; a3.z += w3.z; a3.w += w3.w;
    }
    dst[o0]       = a0;
    dst[o0 + 64]  = a1;
    dst[o0 + 128] = a2;
    dst[o0 + 192] = a3;

    const int u = b * 256 + t;
    if (u < C_IN * D) {
        diff1[u] = 0.f;
        out[u] = fmaxf(x[u], 0.f) + bc2[u >> 9];   // residual + stage-2 bias
    }
}

// ---------------------------------------------------------------------------
// K2: 64 blocks x 256, 16 cols/block. Blocks 0..31: stage-1 argmax over the
// sum of 16 W1-planes, then scatter diff1[c,n] += W1[c,n,i]*relu(x[c,i]).
// Blocks 32..63: stage-2 argmax over sum of 8 W2-planes -> node2, pre-gather
// w2v[c,i] = W2[c,n_i,i]. Tie-break = first (smallest o) = jnp.argmax.
// ---------------------------------------------------------------------------
__global__ __launch_bounds__(256)
void argmax_scatter_kernel(const float* __restrict__ Sp,
                           const float* __restrict__ W1,
                           const float* __restrict__ W2,
                           const float* __restrict__ x,
                           float* __restrict__ diff1,
                           float* __restrict__ w2v,
                           int* __restrict__ node2) {
    __shared__ float lv[256];
    __shared__ int   li[256];
    __shared__ int   node_s[16];

    const int  tid = threadIdx.x;
    const bool st1 = blockIdx.x < 32;
    const int  i0  = (blockIdx.x & 31) * 16;
    const int  il  = tid & 15;
    const int  ol  = tid >> 4;                     // 0..15
    const float* __restrict__ base = st1 ? Sp : Sp + (size_t)16 * DD;

    float best = -__builtin_inff();
    int   bidx = D;                                // > any valid o
    for (int k = 0; k < 32; ++k) {
        const int o   = ol + (k << 4);             // ascending per thread
        const int off = o * D + i0 + il;
        float v = 0.f;
        if (st1) {
#pragma unroll
            for (int pl = 0; pl < 16; ++pl) v += base[(size_t)pl * DD + off];
        } else {
#pragma unroll
            for (int pl = 0; pl < 8; ++pl)  v += base[(size_t)pl * DD + off];
        }
        if (v > best) { best = v; bidx = o; }      // strict >: first wins
    }
    lv[tid] = best; li[tid] = bidx;
    __syncthreads();
    for (int s = 128; s >= 16; s >>= 1) {
        if (tid < s) {
            float v2 = lv[tid + s]; int i2 = li[tid + s];
            if (v2 > lv[tid] || (v2 == lv[tid] && i2 < li[tid])) {
                lv[tid] = v2; li[tid] = i2;
            }
        }
        __syncthreads();
    }
    if (tid < 16) {
        node_s[tid] = li[tid];
        if (!st1) node2[i0 + tid] = li[tid];
    }
    __syncthreads();

    if (st1) {
        for (int idx = tid; idx < C_IN * 16; idx += 256) {
            int ii = idx & 15;
            int c  = idx >> 4;
            int i  = i0 + ii;
            int n  = node_s[ii];
            float xv = fmaxf(x[c * D + i], 0.f);
            float w  = W1[(size_t)c * DD + (size_t)n * D + i];
            atomicAdd(&diff1[c * D + n], w * xv);
        }
    } else {
        for (int idx = tid; idx < C_RES * 16; idx += 256) {
            int ii = idx & 15;
            int c  = idx >> 4;
            int i  = i0 + ii;
            int n  = node_s[ii];
            w2v[c * D + i] = W2[(size_t)c * DD + (size_t)n * D + i];
        }
    }
}

// ---------------------------------------------------------------------------
// K3 (fused conv1+conv2+scatter), unchanged from round 4 (passed, absmax 0):
//   x2[c,i] = relu(bc1[c] + sum_cc Wc1[c,cc]*diff1[cc,i])
//   t[c,i]  = w2v[c,i] * x2[c,i]
//   out[o, node2[i]] += sum_c Wc2[o,c] * t[c,i]   (out pre-init'd)
// 64 blocks x 256, 8 cols/block.
// ---------------------------------------------------------------------------
__global__ __launch_bounds__(256)
void tail_kernel(const float* __restrict__ Wc1,
                 const float* __restrict__ bc1,
                 const float* __restrict__ diff1,
                 const float* __restrict__ w2v,
                 const int* __restrict__ node2,
                 const float* __restrict__ Wc2,
                 float* __restrict__ out) {
    __shared__ float wc1s[C_RES][C_IN + 1];
    __shared__ float d1s[C_IN][8];
    __shared__ float ts[C_RES][9];
    __shared__ int   nds[8];

    const int tid = threadIdx.x;
    const int i0  = blockIdx.x * 8;

    for (int idx = tid; idx < C_RES * C_IN; idx += 256)
        wc1s[idx >> 7][idx & 127] = Wc1[idx];
    for (int idx = tid; idx < C_IN * 8; idx += 256)
        d1s[idx >> 3][idx & 7] = diff1[(idx >> 3) * D + i0 + (idx & 7)];
    if (tid < 8) nds[tid] = node2[i0 + tid];
    __syncthreads();

    {   // Phase A: thread (c = tid&63, j = tid>>6) handles i = 2j, 2j+1
        const int c = tid & 63;
        const int j = tid >> 6;
        float a0 = bc1[c];
        float a1 = a0;
#pragma unroll 8
        for (int cc = 0; cc < C_IN; ++cc) {
            float w = wc1s[c][cc];
            a0 += w * d1s[cc][2 * j];
            a1 += w * d1s[cc][2 * j + 1];
        }
        ts[c][2 * j]     = w2v[c * D + i0 + 2 * j]     * fmaxf(a0, 0.f);
        ts[c][2 * j + 1] = w2v[c * D + i0 + 2 * j + 1] * fmaxf(a1, 0.f);
    }
    __syncthreads();

    {   // Phase B: thread (o = tid>>1, h = tid&1) handles i = 4h..4h+3
        const int o = tid >> 1;
        const int h = tid & 1;
        float z0 = 0.f, z1 = 0.f, z2 = 0.f, z3 = 0.f;
#pragma unroll 8
        for (int c = 0; c < C_RES; ++c) {
            float w = Wc2[o * C_RES + c];
            z0 += w * ts[c][4 * h];
            z1 += w * ts[c][4 * h + 1];
            z2 += w * ts[c][4 * h + 2];
            z3 += w * ts[c][4 * h + 3];
        }
        atomicAdd(&out[o * D + nds[4 * h]],     z0);
        atomicAdd(&out[o * D + nds[4 * h + 1]], z1);
        atomicAdd(&out[o * D + nds[4 * h + 2]], z2);
        atomicAdd(&out[o * D + nds[4 * h + 3]], z3);
    }
}

extern "C" void kernel_launch(void* const* d_in, const int* in_sizes, int n_in,
                              void* d_out, int out_size, void* d_ws, size_t ws_size,
                              hipStream_t stream) {
    const float* x   = (const float*)d_in[0];   // (1, 128, 512)
    const float* W1  = (const float*)d_in[1];   // (128, 512, 512)
    const float* Wc1 = (const float*)d_in[2];   // (64, 128)
    const float* bc1 = (const float*)d_in[3];   // (64,)
    const float* W2  = (const float*)d_in[4];   // (64, 512, 512)
    const float* Wc2 = (const float*)d_in[5];   // (128, 64)
    const float* bc2 = (const float*)d_in[6];   // (128,)
    float* out = (float*)d_out;                 // (1, 128, 512) fp32

    float* ws    = (float*)d_ws;
    float* Sp    = ws;                          // 24 * DD floats (25.2 MB)
    float* diff1 = Sp + (size_t)24 * DD;        // 65536
    float* w2v   = diff1 + C_IN * D;            // 32768
    int*   node2 = (int*)(w2v + C_RES * D);     // 512

    // K1: stream W1+W2 (201 MB) -> 24 partial planes; zero diff1; init out
    sum_init_kernel<<<1536, 256, 0, stream>>>(W1, W2, x, bc2, Sp, diff1, out);
    // K2: argmax both stages + stage-1 scatter + stage-2 W-gather
    argmax_scatter_kernel<<<64, 256, 0, stream>>>(Sp, W1, W2, x,
                                                  diff1, w2v, node2);
    // K3: conv1(+bias,relu) -> conv2 -> scatter-add into pre-init'd out
    tail_kernel<<<64, 256, 0, stream>>>(Wc1, bc1, diff1, w2v, node2, Wc2, out);
}